// Round 4
// baseline (635.247 us; speedup 1.0000x reference)
//
#include <hip/hip_runtime.h>
#include <hip/hip_bf16.h>

// ---------------------------------------------------------------------------
// GAE: 2x GCNConv (self-loops, sym-norm) + edge dot decoder.
// R3->R4: scatter_k was write-amplification-bound (147MB HBM writes for
// 12.8MB payload). Fix: (a) fuse col+wgt into one uint2 record (1 write/edge),
// (b) bucket the scatter into 8 dst-range passes so the active write window
// (1.6MB) is L2-resident and lines fill before eviction.
// ---------------------------------------------------------------------------

#define CHUNK 512  // scan chunk
#define NPASS 8    // scatter bucketing passes

__device__ __forceinline__ unsigned short f2bf_rne(float f) {
  unsigned int b = __float_as_uint(f);
  b += 0x7FFFu + ((b >> 16) & 1u);
  return (unsigned short)(b >> 16);
}
__device__ __forceinline__ float bf_lo(unsigned int u) {  // low 16 bits -> float
  return __uint_as_float(u << 16);
}
__device__ __forceinline__ float bf_hi(unsigned int u) {  // high 16 bits -> float
  return __uint_as_float(u & 0xFFFF0000u);
}

__global__ void init_k(int* __restrict__ cnt, int* __restrict__ fill, int n) {
  int i = blockIdx.x * blockDim.x + threadIdx.x;
  if (i < n) { cnt[i] = 0; fill[i] = 0; }
}

__global__ void count_k(const int* __restrict__ dst, int* __restrict__ cnt, int E) {
  int i = blockIdx.x * blockDim.x + threadIdx.x;
  if (i < E) atomicAdd(&cnt[dst[i]], 1);
}

__global__ void dis_k(const int* __restrict__ cnt, float* __restrict__ dis, int n) {
  int i = blockIdx.x * blockDim.x + threadIdx.x;
  if (i < n) dis[i] = rsqrtf((float)(cnt[i] + 1));  // +1: self loop
}

// per-chunk exclusive scan; chunk totals to bsum
__global__ void chunk_scan_k(const int* __restrict__ cnt, int* __restrict__ rp,
                             int* __restrict__ bsum, int n) {
  __shared__ int s[CHUNK];
  int t = threadIdx.x, b = blockIdx.x;
  int i = b * CHUNK + t;
  int v = (i < n) ? cnt[i] : 0;
  s[t] = v;
  __syncthreads();
  for (int off = 1; off < CHUNK; off <<= 1) {
    int u = (t >= off) ? s[t - off] : 0;
    __syncthreads();
    s[t] += u;
    __syncthreads();
  }
  if (i < n) rp[i] = s[t] - v;  // local exclusive
  if (t == CHUNK - 1) bsum[b] = s[t];
}

// single block: exclusive-scan chunk sums in place; write rp[n] = total
__global__ void scan_sums_k(int* __restrict__ bsum, int* __restrict__ rp,
                            int nchunks, int n) {
  __shared__ int s[CHUNK];
  int t = threadIdx.x;
  int v = (t < nchunks) ? bsum[t] : 0;
  s[t] = v;
  __syncthreads();
  for (int off = 1; off < CHUNK; off <<= 1) {
    int u = (t >= off) ? s[t - off] : 0;
    __syncthreads();
    s[t] += u;
    __syncthreads();
  }
  if (t < nchunks) bsum[t] = s[t] - v;  // exclusive
  if (t == nchunks - 1) rp[n] = s[t];   // grand total = E
}

__global__ void add_off_k(int* __restrict__ rp, const int* __restrict__ bsum, int n) {
  int i = blockIdx.x * CHUNK + threadIdx.x;
  if (i < n) rp[i] += bsum[blockIdx.x];
}

// bucketed scatter: only edges with dst in [lo,hi) write this pass.
// Write window = (E/NPASS)*8B ~ 1.6MB -> L2-resident, lines fill before evict.
__global__ void scatter_pass_k(const int* __restrict__ src, const int* __restrict__ dst,
                               const int* __restrict__ rp, int* __restrict__ fill,
                               const float* __restrict__ dis, uint2* __restrict__ edges,
                               int E, int lo, int hi) {
  int i = blockIdx.x * blockDim.x + threadIdx.x;
  if (i >= E) return;
  int d = dst[i];
  if (d < lo || d >= hi) return;
  int s = src[i];
  int pos = rp[d] + atomicAdd(&fill[d], 1);
  float w = dis[s] * dis[d];
  edges[pos] = make_uint2((unsigned)s, __float_as_uint(w));
}

// ---------------- fp32 tiled GEMM: C[M,N] = A[M,K] @ B[K,N] -----------------
// 256 threads as 16x16; thread tile RM x RN (RN==8); K-tile 16.
// OBF: store C as bf16 (packed uint4 of 8 bf16), else fp32 float4.
template <int TM, int TN, int RM, int RN, bool OBF>
__launch_bounds__(256) __global__
void sgemm_k(const float* __restrict__ A, const float* __restrict__ B,
             void* __restrict__ Cv, int M, int N, int K) {
  const int TK = 16;
  __shared__ float As[TK][TM + 4];  // transposed: As[k][m]
  __shared__ float Bs[TK][TN + 4];
  int t = threadIdx.x;
  int tx = t & 15, ty = t >> 4;
  int m0 = blockIdx.y * TM, n0 = blockIdx.x * TN;
  float acc[RM][RN] = {};
  const int AU = TM / 64;
  const int BU = TN / 64;
  for (int k0 = 0; k0 < K; k0 += TK) {
    float4 aldg[AU], bldg[BU];
#pragma unroll
    for (int u = 0; u < AU; u++) {
      int idx = t + u * 256;
      int row = idx >> 2, kq = (idx & 3) * 4;
      int gr = m0 + row;
      aldg[u] = make_float4(0.f, 0.f, 0.f, 0.f);
      if (gr < M) aldg[u] = *reinterpret_cast<const float4*>(A + (size_t)gr * K + k0 + kq);
    }
#pragma unroll
    for (int u = 0; u < BU; u++) {
      int idx = t + u * 256;
      int row = idx / (TN / 4), cq = (idx % (TN / 4)) * 4;
      bldg[u] = *reinterpret_cast<const float4*>(B + (size_t)(k0 + row) * N + n0 + cq);
    }
    __syncthreads();
#pragma unroll
    for (int u = 0; u < AU; u++) {
      int idx = t + u * 256;
      int row = idx >> 2, kq = (idx & 3) * 4;
      As[kq + 0][row] = aldg[u].x;
      As[kq + 1][row] = aldg[u].y;
      As[kq + 2][row] = aldg[u].z;
      As[kq + 3][row] = aldg[u].w;
    }
#pragma unroll
    for (int u = 0; u < BU; u++) {
      int idx = t + u * 256;
      int row = idx / (TN / 4), cq = (idx % (TN / 4)) * 4;
      *reinterpret_cast<float4*>(&Bs[row][cq]) = bldg[u];
    }
    __syncthreads();
#pragma unroll
    for (int k = 0; k < TK; k++) {
      float a[RM], b[RN];
#pragma unroll
      for (int i = 0; i < RM; i += 4)
        *reinterpret_cast<float4*>(&a[i]) = *reinterpret_cast<const float4*>(&As[k][ty * RM + i]);
#pragma unroll
      for (int j = 0; j < RN; j += 4)
        *reinterpret_cast<float4*>(&b[j]) = *reinterpret_cast<const float4*>(&Bs[k][tx * RN + j]);
#pragma unroll
      for (int i = 0; i < RM; i++)
#pragma unroll
        for (int j = 0; j < RN; j++) acc[i][j] = fmaf(a[i], b[j], acc[i][j]);
    }
  }
#pragma unroll
  for (int i = 0; i < RM; i++) {
    int r = m0 + ty * RM + i;
    if (r >= M) continue;
    if (OBF) {
      unsigned short u[RN];
#pragma unroll
      for (int j = 0; j < RN; j++) u[j] = f2bf_rne(acc[i][j]);
      unsigned short* C = (unsigned short*)Cv;
      *reinterpret_cast<uint4*>(C + (size_t)r * N + n0 + tx * RN) =
          *reinterpret_cast<const uint4*>(u);
    } else {
      float* C = (float*)Cv;
#pragma unroll
      for (int j = 0; j < RN; j += 4) {
        float4 o = make_float4(acc[i][j], acc[i][j + 1], acc[i][j + 2], acc[i][j + 3]);
        *reinterpret_cast<float4*>(C + (size_t)r * N + n0 + tx * RN + j) = o;
      }
    }
  }
}

// ------------- CSR aggregation over bf16 h: fp32 accumulate ----------------
// out[d] = sum_e w_e*h[src_e] + dis^2*h[d] + b  (fp32 out)
// edges[e] = {src, float_bits(w)} fused record (one 8B load per edge).
template <int VEC, bool RELU>
__launch_bounds__(256) __global__
void aggregate_k(const unsigned short* __restrict__ h, const int* __restrict__ rp,
                 const uint2* __restrict__ edges, const float* __restrict__ dis,
                 const float* __restrict__ bias, float* __restrict__ out, int n) {
  const int DIM = VEC * 64;
  const int PF = 8;
  int wave = threadIdx.x >> 6, lane = threadIdx.x & 63;
  int node = blockIdx.x * (blockDim.x >> 6) + wave;
  if (node >= n) return;
  int start = rp[node], end = rp[node + 1];
  float di = dis[node];
  float sw = di * di;
  float acc[VEC];
  {  // self loop
    const unsigned short* hp = h + (size_t)node * DIM + lane * VEC;
    if (VEC == 4) {
      uint2 r = *reinterpret_cast<const uint2*>(hp);
      acc[0] = bf_lo(r.x) * sw; acc[1] = bf_hi(r.x) * sw;
      acc[2] = bf_lo(r.y) * sw; acc[3] = bf_hi(r.y) * sw;
    } else {
      unsigned int r = *reinterpret_cast<const unsigned int*>(hp);
      acc[0] = bf_lo(r) * sw; acc[1] = bf_hi(r) * sw;
    }
  }
  int e = start;
  for (; e + PF <= end; e += PF) {
    uint2 ew[PF];
#pragma unroll
    for (int j = 0; j < PF; j++) ew[j] = edges[e + j];
    if (VEC == 4) {
      uint2 r[PF];
#pragma unroll
      for (int j = 0; j < PF; j++)
        r[j] = *reinterpret_cast<const uint2*>(h + (size_t)ew[j].x * DIM + lane * 4);
#pragma unroll
      for (int j = 0; j < PF; j++) {
        float w = __uint_as_float(ew[j].y);
        acc[0] = fmaf(bf_lo(r[j].x), w, acc[0]);
        acc[1] = fmaf(bf_hi(r[j].x), w, acc[1]);
        acc[2] = fmaf(bf_lo(r[j].y), w, acc[2]);
        acc[3] = fmaf(bf_hi(r[j].y), w, acc[3]);
      }
    } else {
      unsigned int r[PF];
#pragma unroll
      for (int j = 0; j < PF; j++)
        r[j] = *reinterpret_cast<const unsigned int*>(h + (size_t)ew[j].x * DIM + lane * 2);
#pragma unroll
      for (int j = 0; j < PF; j++) {
        float w = __uint_as_float(ew[j].y);
        acc[0] = fmaf(bf_lo(r[j]), w, acc[0]);
        acc[1] = fmaf(bf_hi(r[j]), w, acc[1]);
      }
    }
  }
  for (; e < end; e++) {
    uint2 ew = edges[e];
    float w = __uint_as_float(ew.y);
    const unsigned short* hs = h + (size_t)ew.x * DIM + lane * VEC;
    if (VEC == 4) {
      uint2 r = *reinterpret_cast<const uint2*>(hs);
      acc[0] = fmaf(bf_lo(r.x), w, acc[0]);
      acc[1] = fmaf(bf_hi(r.x), w, acc[1]);
      acc[2] = fmaf(bf_lo(r.y), w, acc[2]);
      acc[3] = fmaf(bf_hi(r.y), w, acc[3]);
    } else {
      unsigned int r = *reinterpret_cast<const unsigned int*>(hs);
      acc[0] = fmaf(bf_lo(r), w, acc[0]);
      acc[1] = fmaf(bf_hi(r), w, acc[1]);
    }
  }
  float* op = out + (size_t)node * DIM + lane * VEC;
#pragma unroll
  for (int v = 0; v < VEC; v++) {
    float r = acc[v] + bias[lane * VEC + v];
    if (RELU) r = fmaxf(r, 0.f);
    op[v] = r;
  }
}

// --------------- decode: y[e] = dot(z[a], z[b]) over 128 dims ---------------
__launch_bounds__(256) __global__
void decode_k(const float* __restrict__ z, const int* __restrict__ ea,
              const int* __restrict__ eb, float* __restrict__ y, int E) {
  int wave = threadIdx.x >> 6, lane = threadIdx.x & 63;
  int e = blockIdx.x * (blockDim.x >> 6) + wave;
  if (e >= E) return;
  int a = ea[e], b = eb[e];
  const float2* za = reinterpret_cast<const float2*>(z + (size_t)a * 128);
  const float2* zb = reinterpret_cast<const float2*>(z + (size_t)b * 128);
  float2 pa = za[lane], pb = zb[lane];
  float s = pa.x * pb.x + pa.y * pb.y;
#pragma unroll
  for (int off = 32; off; off >>= 1) s += __shfl_down(s, off);
  if (lane == 0) y[e] = s;
}

extern "C" void kernel_launch(void* const* d_in, const int* in_sizes, int n_in,
                              void* d_out, int out_size, void* d_ws, size_t ws_size,
                              hipStream_t stream) {
  const float* x = (const float*)d_in[0];
  const int* ei = (const int*)d_in[1];
  const int* eli = (const int*)d_in[2];
  const float* W1 = (const float*)d_in[3];
  const float* b1 = (const float*)d_in[4];
  const float* W2 = (const float*)d_in[5];
  const float* b2 = (const float*)d_in[6];
  float* y = (float*)d_out;

  const int DIN = 256, DH = 256, DOUT = 128;
  const int n = in_sizes[0] / DIN;          // 50000
  const int E = in_sizes[1] / 2;            // 1.6M
  const int EL = in_sizes[2] / 2;           // 100k
  const int* src = ei;
  const int* dst = ei + E;
  const int* ea = eli;
  const int* eb = eli + EL;

  // workspace carve-up (256B aligned)
  size_t off = 0;
  auto alloc = [&](size_t bytes) {
    void* p = (char*)d_ws + off;
    off += (bytes + 255) & ~(size_t)255;
    return p;
  };
  int nchunks = (n + CHUNK - 1) / CHUNK;
  int* cnt = (int*)alloc((size_t)n * 4);
  int* fill = (int*)alloc((size_t)n * 4);
  int* rp = (int*)alloc((size_t)(n + 1) * 4);
  int* bsum = (int*)alloc((size_t)(nchunks + 1) * 4);
  float* dis = (float*)alloc((size_t)n * 4);
  uint2* edges = (uint2*)alloc((size_t)E * 8);                      // fused {src, w}
  unsigned short* h1 = (unsigned short*)alloc((size_t)n * DH * 2);  // bf16; reused as h2
  float* z1 = (float*)alloc((size_t)n * DH * 4);                    // fp32; reused as z2
  (void)ws_size;

  // ---- graph prep ----
  init_k<<<(n + 255) / 256, 256, 0, stream>>>(cnt, fill, n);
  count_k<<<(E + 255) / 256, 256, 0, stream>>>(dst, cnt, E);
  dis_k<<<(n + 255) / 256, 256, 0, stream>>>(cnt, dis, n);
  chunk_scan_k<<<nchunks, CHUNK, 0, stream>>>(cnt, rp, bsum, n);
  scan_sums_k<<<1, CHUNK, 0, stream>>>(bsum, rp, nchunks, n);
  add_off_k<<<nchunks, CHUNK, 0, stream>>>(rp, bsum, n);
  for (int p = 0; p < NPASS; p++) {
    int lo = (int)((long long)n * p / NPASS);
    int hi = (int)((long long)n * (p + 1) / NPASS);
    scatter_pass_k<<<(E + 255) / 256, 256, 0, stream>>>(src, dst, rp, fill, dis, edges,
                                                        E, lo, hi);
  }

  // ---- conv1: h1 = bf16(x@W1) ; z1 = agg(h1)+b1, relu (fp32) ----
  {
    dim3 grid(DH / 128, (n + 127) / 128);
    sgemm_k<128, 128, 8, 8, true><<<grid, 256, 0, stream>>>(x, W1, h1, n, DH, DIN);
  }
  aggregate_k<4, true><<<(n + 3) / 4, 256, 0, stream>>>(h1, rp, edges, dis, b1, z1, n);

  // ---- conv2: h2 = bf16(z1@W2) ; z2 = agg(h2)+b2 (fp32) ----
  unsigned short* h2 = h1;  // h1 no longer needed
  {
    dim3 grid(DOUT / 128, (n + 63) / 64);
    sgemm_k<64, 128, 4, 8, true><<<grid, 256, 0, stream>>>(z1, W2, h2, n, DOUT, DH);
  }
  float* z2 = z1;  // stream-ordered: gemm2 consumed z1 before agg2 overwrites
  aggregate_k<2, false><<<(n + 3) / 4, 256, 0, stream>>>(h2, rp, edges, dis, b2, z2, n);

  // ---- decode ----
  decode_k<<<(EL + 3) / 4, 256, 0, stream>>>(z2, ea, eb, y, EL);
}

// Round 5
// 535.334 us; speedup vs baseline: 1.1866x; 1.1866x over previous
//
#include <hip/hip_runtime.h>
#include <hip/hip_bf16.h>

// ---------------------------------------------------------------------------
// GAE: 2x GCNConv (self-loops, sym-norm) + edge dot decoder.
// R4->R5: both GEMMs moved to bf16 MFMA (16x16x32), 128x128 block tile,
// 2x2 waves of 64x64, LDS row stride padded to 40 shorts (kills stride-32
// bank aliasing). x/W converted to bf16 (W transposed to [N][K]); agg1 now
// writes z1 as bf16 (feeds gemm2 A-operand). fp32 accumulate everywhere.
// ---------------------------------------------------------------------------

#define CHUNK 512  // scan chunk
#define NPASS 8    // scatter bucketing passes

typedef __attribute__((ext_vector_type(8))) short short8;
typedef __attribute__((ext_vector_type(4))) float f32x4;

__device__ __forceinline__ unsigned short f2bf_rne(float f) {
  unsigned int b = __float_as_uint(f);
  b += 0x7FFFu + ((b >> 16) & 1u);
  return (unsigned short)(b >> 16);
}
__device__ __forceinline__ float bf_lo(unsigned int u) {  // low 16 bits -> float
  return __uint_as_float(u << 16);
}
__device__ __forceinline__ float bf_hi(unsigned int u) {  // high 16 bits -> float
  return __uint_as_float(u & 0xFFFF0000u);
}

__global__ void init_k(int* __restrict__ cnt, int* __restrict__ fill, int n) {
  int i = blockIdx.x * blockDim.x + threadIdx.x;
  if (i < n) { cnt[i] = 0; fill[i] = 0; }
}

__global__ void count_k(const int* __restrict__ dst, int* __restrict__ cnt, int E) {
  int i = blockIdx.x * blockDim.x + threadIdx.x;
  if (i < E) atomicAdd(&cnt[dst[i]], 1);
}

__global__ void dis_k(const int* __restrict__ cnt, float* __restrict__ dis, int n) {
  int i = blockIdx.x * blockDim.x + threadIdx.x;
  if (i < n) dis[i] = rsqrtf((float)(cnt[i] + 1));  // +1: self loop
}

__global__ void chunk_scan_k(const int* __restrict__ cnt, int* __restrict__ rp,
                             int* __restrict__ bsum, int n) {
  __shared__ int s[CHUNK];
  int t = threadIdx.x, b = blockIdx.x;
  int i = b * CHUNK + t;
  int v = (i < n) ? cnt[i] : 0;
  s[t] = v;
  __syncthreads();
  for (int off = 1; off < CHUNK; off <<= 1) {
    int u = (t >= off) ? s[t - off] : 0;
    __syncthreads();
    s[t] += u;
    __syncthreads();
  }
  if (i < n) rp[i] = s[t] - v;  // local exclusive
  if (t == CHUNK - 1) bsum[b] = s[t];
}

__global__ void scan_sums_k(int* __restrict__ bsum, int* __restrict__ rp,
                            int nchunks, int n) {
  __shared__ int s[CHUNK];
  int t = threadIdx.x;
  int v = (t < nchunks) ? bsum[t] : 0;
  s[t] = v;
  __syncthreads();
  for (int off = 1; off < CHUNK; off <<= 1) {
    int u = (t >= off) ? s[t - off] : 0;
    __syncthreads();
    s[t] += u;
    __syncthreads();
  }
  if (t < nchunks) bsum[t] = s[t] - v;  // exclusive
  if (t == nchunks - 1) rp[n] = s[t];   // grand total = E
}

__global__ void add_off_k(int* __restrict__ rp, const int* __restrict__ bsum, int n) {
  int i = blockIdx.x * CHUNK + threadIdx.x;
  if (i < n) rp[i] += bsum[blockIdx.x];
}

// bucketed scatter: only edges with dst in [lo,hi) write this pass.
__global__ void scatter_pass_k(const int* __restrict__ src, const int* __restrict__ dst,
                               const int* __restrict__ rp, int* __restrict__ fill,
                               const float* __restrict__ dis, uint2* __restrict__ edges,
                               int E, int lo, int hi) {
  int i = blockIdx.x * blockDim.x + threadIdx.x;
  if (i >= E) return;
  int d = dst[i];
  if (d < lo || d >= hi) return;
  int s = src[i];
  int pos = rp[d] + atomicAdd(&fill[d], 1);
  float w = dis[s] * dis[d];
  edges[pos] = make_uint2((unsigned)s, __float_as_uint(w));
}

// ---- fp32 -> bf16 bulk convert (n multiple of 4) ----
__global__ void cvt_bf_k(const float* __restrict__ in, unsigned short* __restrict__ out,
                         int n4) {
  int i = blockIdx.x * blockDim.x + threadIdx.x;
  if (i >= n4) return;
  float4 v = *reinterpret_cast<const float4*>(in + (size_t)i * 4);
  unsigned int p0 = (unsigned int)f2bf_rne(v.x) | ((unsigned int)f2bf_rne(v.y) << 16);
  unsigned int p1 = (unsigned int)f2bf_rne(v.z) | ((unsigned int)f2bf_rne(v.w) << 16);
  *reinterpret_cast<uint2*>(out + (size_t)i * 4) = make_uint2(p0, p1);
}

// ---- W [K][N] fp32 -> Wt [N][K] bf16 (tiny) ----
__global__ void cvt_wt_k(const float* __restrict__ W, unsigned short* __restrict__ Wt,
                         int K, int N) {
  int i = blockIdx.x * blockDim.x + threadIdx.x;
  if (i >= K * N) return;
  int k = i / N, n = i % N;
  Wt[(size_t)n * K + k] = f2bf_rne(W[i]);
}

// ---------------- bf16 MFMA GEMM: C[M,N] = A[M,K] @ Bt[N,K]^T ---------------
// 256 threads = 4 waves (2x2 of 64x64). Block tile 128x128, K-step 32.
// LDS row stride 40 shorts (80B): 16B-aligned rows, no stride-32 bank alias.
#define LDST 40
__launch_bounds__(256) __global__
void bfgemm_k(const unsigned short* __restrict__ A,   // [M][K] bf16
              const unsigned short* __restrict__ Bt,  // [N][K] bf16
              unsigned short* __restrict__ C,         // [M][N] bf16
              int M, int N, int K) {
  __shared__ short As[128 * LDST];
  __shared__ short Bs[128 * LDST];
  int t = threadIdx.x;
  int lane = t & 63, wave = t >> 6;
  int quad = lane >> 4, l16 = lane & 15;
  int wm = (wave & 1) * 64, wn = (wave >> 1) * 64;
  int m0 = blockIdx.y * 128, n0 = blockIdx.x * 128;
  f32x4 acc[4][4];
#pragma unroll
  for (int i = 0; i < 4; i++)
#pragma unroll
    for (int j = 0; j < 4; j++) acc[i][j] = (f32x4)0.f;

  for (int k0 = 0; k0 < K; k0 += 32) {
    uint4 av[2], bv[2];
#pragma unroll
    for (int u = 0; u < 2; u++) {
      int idx = t + u * 256;
      int row = idx >> 2, c8 = (idx & 3) * 8;
      int gr = m0 + row;
      av[u] = make_uint4(0u, 0u, 0u, 0u);
      if (gr < M)
        av[u] = *reinterpret_cast<const uint4*>(A + (size_t)gr * K + k0 + c8);
      bv[u] = *reinterpret_cast<const uint4*>(Bt + (size_t)(n0 + row) * K + k0 + c8);
    }
    __syncthreads();  // prior tile's frag reads done
#pragma unroll
    for (int u = 0; u < 2; u++) {
      int idx = t + u * 256;
      int row = idx >> 2, c8 = (idx & 3) * 8;
      *reinterpret_cast<uint4*>(&As[row * LDST + c8]) = av[u];
      *reinterpret_cast<uint4*>(&Bs[row * LDST + c8]) = bv[u];
    }
    __syncthreads();
    short8 af[4], bfr[4];
#pragma unroll
    for (int mt = 0; mt < 4; mt++)
      af[mt] = *reinterpret_cast<const short8*>(&As[(wm + mt * 16 + l16) * LDST + quad * 8]);
#pragma unroll
    for (int nt = 0; nt < 4; nt++)
      bfr[nt] = *reinterpret_cast<const short8*>(&Bs[(wn + nt * 16 + l16) * LDST + quad * 8]);
#pragma unroll
    for (int mt = 0; mt < 4; mt++)
#pragma unroll
      for (int nt = 0; nt < 4; nt++)
        acc[mt][nt] = __builtin_amdgcn_mfma_f32_16x16x32_bf16(af[mt], bfr[nt], acc[mt][nt], 0, 0, 0);
  }
  // epilogue: D row = quad*4 + r, col = l16 (per 16x16 tile)
#pragma unroll
  for (int mt = 0; mt < 4; mt++) {
#pragma unroll
    for (int r = 0; r < 4; r++) {
      int grow = m0 + wm + mt * 16 + quad * 4 + r;
      if (grow >= M) continue;
      unsigned short* cp = C + (size_t)grow * N + n0 + wn + l16;
#pragma unroll
      for (int nt = 0; nt < 4; nt++) cp[nt * 16] = f2bf_rne(acc[mt][nt][r]);
    }
  }
}

// ------------- CSR aggregation over bf16 h: fp32 accumulate ----------------
// out[d] = sum_e w_e*h[src_e] + dis^2*h[d] + b ; OBF -> bf16 out else fp32.
template <int VEC, bool RELU, bool OBF>
__launch_bounds__(256) __global__
void aggregate_k(const unsigned short* __restrict__ h, const int* __restrict__ rp,
                 const uint2* __restrict__ edges, const float* __restrict__ dis,
                 const float* __restrict__ bias, void* __restrict__ outv, int n) {
  const int DIM = VEC * 64;
  const int PF = 8;
  int wave = threadIdx.x >> 6, lane = threadIdx.x & 63;
  int node = blockIdx.x * (blockDim.x >> 6) + wave;
  if (node >= n) return;
  int start = rp[node], end = rp[node + 1];
  float di = dis[node];
  float sw = di * di;
  float acc[VEC];
  {  // self loop
    const unsigned short* hp = h + (size_t)node * DIM + lane * VEC;
    if (VEC == 4) {
      uint2 r = *reinterpret_cast<const uint2*>(hp);
      acc[0] = bf_lo(r.x) * sw; acc[1] = bf_hi(r.x) * sw;
      acc[2] = bf_lo(r.y) * sw; acc[3] = bf_hi(r.y) * sw;
    } else {
      unsigned int r = *reinterpret_cast<const unsigned int*>(hp);
      acc[0] = bf_lo(r) * sw; acc[1] = bf_hi(r) * sw;
    }
  }
  int e = start;
  for (; e + PF <= end; e += PF) {
    uint2 ew[PF];
#pragma unroll
    for (int j = 0; j < PF; j++) ew[j] = edges[e + j];
    if (VEC == 4) {
      uint2 r[PF];
#pragma unroll
      for (int j = 0; j < PF; j++)
        r[j] = *reinterpret_cast<const uint2*>(h + (size_t)ew[j].x * DIM + lane * 4);
#pragma unroll
      for (int j = 0; j < PF; j++) {
        float w = __uint_as_float(ew[j].y);
        acc[0] = fmaf(bf_lo(r[j].x), w, acc[0]);
        acc[1] = fmaf(bf_hi(r[j].x), w, acc[1]);
        acc[2] = fmaf(bf_lo(r[j].y), w, acc[2]);
        acc[3] = fmaf(bf_hi(r[j].y), w, acc[3]);
      }
    } else {
      unsigned int r[PF];
#pragma unroll
      for (int j = 0; j < PF; j++)
        r[j] = *reinterpret_cast<const unsigned int*>(h + (size_t)ew[j].x * DIM + lane * 2);
#pragma unroll
      for (int j = 0; j < PF; j++) {
        float w = __uint_as_float(ew[j].y);
        acc[0] = fmaf(bf_lo(r[j]), w, acc[0]);
        acc[1] = fmaf(bf_hi(r[j]), w, acc[1]);
      }
    }
  }
  for (; e < end; e++) {
    uint2 ew = edges[e];
    float w = __uint_as_float(ew.y);
    const unsigned short* hs = h + (size_t)ew.x * DIM + lane * VEC;
    if (VEC == 4) {
      uint2 r = *reinterpret_cast<const uint2*>(hs);
      acc[0] = fmaf(bf_lo(r.x), w, acc[0]);
      acc[1] = fmaf(bf_hi(r.x), w, acc[1]);
      acc[2] = fmaf(bf_lo(r.y), w, acc[2]);
      acc[3] = fmaf(bf_hi(r.y), w, acc[3]);
    } else {
      unsigned int r = *reinterpret_cast<const unsigned int*>(hs);
      acc[0] = fmaf(bf_lo(r), w, acc[0]);
      acc[1] = fmaf(bf_hi(r), w, acc[1]);
    }
  }
#pragma unroll
  for (int v = 0; v < VEC; v++) {
    float r = acc[v] + bias[lane * VEC + v];
    if (RELU) r = fmaxf(r, 0.f);
    acc[v] = r;
  }
  if (OBF) {
    unsigned short* op = (unsigned short*)outv + (size_t)node * DIM + lane * VEC;
    if (VEC == 4) {
      unsigned int p0 = (unsigned int)f2bf_rne(acc[0]) | ((unsigned int)f2bf_rne(acc[1]) << 16);
      unsigned int p1 = (unsigned int)f2bf_rne(acc[2]) | ((unsigned int)f2bf_rne(acc[3]) << 16);
      *reinterpret_cast<uint2*>(op) = make_uint2(p0, p1);
    } else {
      unsigned int p0 = (unsigned int)f2bf_rne(acc[0]) | ((unsigned int)f2bf_rne(acc[1]) << 16);
      *reinterpret_cast<unsigned int*>(op) = p0;
    }
  } else {
    float* op = (float*)outv + (size_t)node * DIM + lane * VEC;
#pragma unroll
    for (int v = 0; v < VEC; v++) op[v] = acc[v];
  }
}

// --------------- decode: y[e] = dot(z[a], z[b]) over 128 dims ---------------
__launch_bounds__(256) __global__
void decode_k(const float* __restrict__ z, const int* __restrict__ ea,
              const int* __restrict__ eb, float* __restrict__ y, int E) {
  int wave = threadIdx.x >> 6, lane = threadIdx.x & 63;
  int e = blockIdx.x * (blockDim.x >> 6) + wave;
  if (e >= E) return;
  int a = ea[e], b = eb[e];
  const float2* za = reinterpret_cast<const float2*>(z + (size_t)a * 128);
  const float2* zb = reinterpret_cast<const float2*>(z + (size_t)b * 128);
  float2 pa = za[lane], pb = zb[lane];
  float s = pa.x * pb.x + pa.y * pb.y;
#pragma unroll
  for (int off = 32; off; off >>= 1) s += __shfl_down(s, off);
  if (lane == 0) y[e] = s;
}

extern "C" void kernel_launch(void* const* d_in, const int* in_sizes, int n_in,
                              void* d_out, int out_size, void* d_ws, size_t ws_size,
                              hipStream_t stream) {
  const float* x = (const float*)d_in[0];
  const int* ei = (const int*)d_in[1];
  const int* eli = (const int*)d_in[2];
  const float* W1 = (const float*)d_in[3];
  const float* b1 = (const float*)d_in[4];
  const float* W2 = (const float*)d_in[5];
  const float* b2 = (const float*)d_in[6];
  float* y = (float*)d_out;

  const int DIN = 256, DH = 256, DOUT = 128;
  const int n = in_sizes[0] / DIN;          // 50000
  const int E = in_sizes[1] / 2;            // 1.6M
  const int EL = in_sizes[2] / 2;           // 100k
  const int* src = ei;
  const int* dst = ei + E;
  const int* ea = eli;
  const int* eb = eli + EL;

  // workspace carve-up (256B aligned)
  size_t off = 0;
  auto alloc = [&](size_t bytes) {
    void* p = (char*)d_ws + off;
    off += (bytes + 255) & ~(size_t)255;
    return p;
  };
  int nchunks = (n + CHUNK - 1) / CHUNK;
  int* cnt = (int*)alloc((size_t)n * 4);
  int* fill = (int*)alloc((size_t)n * 4);
  int* rp = (int*)alloc((size_t)(n + 1) * 4);
  int* bsum = (int*)alloc((size_t)(nchunks + 1) * 4);
  float* dis = (float*)alloc((size_t)n * 4);
  uint2* edges = (uint2*)alloc((size_t)E * 8);                       // fused {src, w}
  unsigned short* W1t = (unsigned short*)alloc((size_t)DIN * DH * 2);
  unsigned short* W2t = (unsigned short*)alloc((size_t)DH * DOUT * 2);
  unsigned short* xbf = (unsigned short*)alloc((size_t)n * DIN * 2); // reused as h2
  unsigned short* h1 = (unsigned short*)alloc((size_t)n * DH * 2);   // reused as z2(fp32? no)
  unsigned short* z1b = (unsigned short*)alloc((size_t)n * DH * 2);
  float* z2 = (float*)alloc((size_t)n * DOUT * 4);
  (void)ws_size;

  // ---- graph prep ----
  init_k<<<(n + 255) / 256, 256, 0, stream>>>(cnt, fill, n);
  count_k<<<(E + 255) / 256, 256, 0, stream>>>(dst, cnt, E);
  dis_k<<<(n + 255) / 256, 256, 0, stream>>>(cnt, dis, n);
  chunk_scan_k<<<nchunks, CHUNK, 0, stream>>>(cnt, rp, bsum, n);
  scan_sums_k<<<1, CHUNK, 0, stream>>>(bsum, rp, nchunks, n);
  add_off_k<<<nchunks, CHUNK, 0, stream>>>(rp, bsum, n);
  for (int p = 0; p < NPASS; p++) {
    int lo = (int)((long long)n * p / NPASS);
    int hi = (int)((long long)n * (p + 1) / NPASS);
    scatter_pass_k<<<(E + 255) / 256, 256, 0, stream>>>(src, dst, rp, fill, dis, edges,
                                                        E, lo, hi);
  }

  // ---- converts ----
  cvt_bf_k<<<(n * DIN / 4 + 255) / 256, 256, 0, stream>>>(x, xbf, n * DIN / 4);
  cvt_wt_k<<<(DIN * DH + 255) / 256, 256, 0, stream>>>(W1, W1t, DIN, DH);
  cvt_wt_k<<<(DH * DOUT + 255) / 256, 256, 0, stream>>>(W2, W2t, DH, DOUT);

  // ---- conv1: h1 = bf16(xbf@W1) ; z1b = bf16(agg(h1)+b1, relu) ----
  {
    dim3 grid(DH / 128, (n + 127) / 128);
    bfgemm_k<<<grid, 256, 0, stream>>>(xbf, W1t, h1, n, DH, DIN);
  }
  aggregate_k<4, true, true><<<(n + 3) / 4, 256, 0, stream>>>(h1, rp, edges, dis, b1, z1b, n);

  // ---- conv2: h2 = bf16(z1b@W2) ; z2 = agg(h2)+b2 (fp32) ----
  unsigned short* h2 = xbf;  // xbf dead after conv1 gemm
  {
    dim3 grid(DOUT / 128, (n + 127) / 128);
    bfgemm_k<<<grid, 256, 0, stream>>>(z1b, W2t, h2, n, DOUT, DH);
  }
  aggregate_k<2, false, false><<<(n + 3) / 4, 256, 0, stream>>>(h2, rp, edges, dis, b2, z2, n);

  // ---- decode ----
  decode_k<<<(EL + 3) / 4, 256, 0, stream>>>(z2, ea, eb, y, EL);
}